// Round 1
// baseline (1646.886 us; speedup 1.0000x reference)
//
#include <hip/hip_runtime.h>

#define NL 8
#define NP 1024
#define DM 768
#define FT 4096

typedef short bf16x8 __attribute__((ext_vector_type(8)));
typedef float f32x4  __attribute__((ext_vector_type(4)));
typedef unsigned short u16;

static __device__ __forceinline__ u16 f2bf(float f) {
    union { float f; unsigned int u; } c; c.f = f;
    unsigned int u = c.u;
    u += 0x7fffu + ((u >> 16) & 1u);   // RNE; inputs finite
    return (u16)(u >> 16);
}

// ---------- fp32 -> bf16 convert (8 elems / thread) ----------
__global__ __launch_bounds__(256) void cvt_bf16_k(const float* __restrict__ in,
                                                  u16* __restrict__ out, int n8) {
    int i = blockIdx.x * 256 + threadIdx.x;
    if (i >= n8) return;
    const f32x4* p = (const f32x4*)in + (size_t)2 * i;
    f32x4 a = p[0], b = p[1];
    bf16x8 v;
    v[0] = (short)f2bf(a[0]); v[1] = (short)f2bf(a[1]);
    v[2] = (short)f2bf(a[2]); v[3] = (short)f2bf(a[3]);
    v[4] = (short)f2bf(b[0]); v[5] = (short)f2bf(b[1]);
    v[6] = (short)f2bf(b[2]); v[7] = (short)f2bf(b[3]);
    *((bf16x8*)out + i) = v;
}

// ---------- out[j,b,d] = b_dec[j,d] ----------
__global__ __launch_bounds__(256) void init_out_k(float* __restrict__ out,
                                                  const float* __restrict__ bdec) {
    int i = blockIdx.x * 256 + threadIdx.x;   // one float4 per thread
    int e = i * 4;
    int d = e % DM;
    int j = e / (NP * DM);
    f32x4 v = *(const f32x4*)(bdec + j * DM + d);
    *(f32x4*)(out + e) = v;
}

// ---------- encode: feats[l,b,f] = relu(x[l,b,:]*W_enc[l,f,:] + b_enc[l,f]) ----------
// 128x128 tile, BK=32, bf16 MFMA 16x16x32. LDS rows padded to 40 bf16 (80 B).
__global__ __launch_bounds__(256, 2) void encode_gemm(const u16* __restrict__ xb,
                                                      const u16* __restrict__ wb,
                                                      const float* __restrict__ benc,
                                                      u16* __restrict__ feats) {
    __shared__ u16 Al[128 * 40];
    __shared__ u16 Bl[128 * 40];
    const int l  = blockIdx.y;
    const int mt = blockIdx.x >> 5;        // 0..7
    const int nt = blockIdx.x & 31;        // 0..31
    const int m0 = mt * 128, n0 = nt * 128;
    const int t = threadIdx.x;
    const int lane = t & 63, w = t >> 6;
    const int lm = lane & 15, q = lane >> 4;
    const int wm = w >> 1, wn = w & 1;

    const u16* Ag = xb + (size_t)l * NP * DM + (size_t)(m0 + (t >> 1)) * DM + (t & 1) * 16;
    const u16* Bg = wb + (size_t)l * FT * DM + (size_t)(n0 + (t >> 1)) * DM + (t & 1) * 16;
    u16* Aw = &Al[(t >> 1) * 40 + (t & 1) * 16];
    u16* Bw = &Bl[(t >> 1) * 40 + (t & 1) * 16];

    f32x4 acc[4][4];
#pragma unroll
    for (int a = 0; a < 4; ++a)
#pragma unroll
        for (int b = 0; b < 4; ++b) acc[a][b] = (f32x4){0.f, 0.f, 0.f, 0.f};

    for (int k0 = 0; k0 < DM; k0 += 32) {
        bf16x8 a0 = *(const bf16x8*)(Ag + k0);
        bf16x8 a1 = *(const bf16x8*)(Ag + k0 + 8);
        bf16x8 b0 = *(const bf16x8*)(Bg + k0);
        bf16x8 b1 = *(const bf16x8*)(Bg + k0 + 8);
        __syncthreads();
        *(bf16x8*)Aw = a0; *(bf16x8*)(Aw + 8) = a1;
        *(bf16x8*)Bw = b0; *(bf16x8*)(Bw + 8) = b1;
        __syncthreads();
        bf16x8 af[4], bfr[4];
#pragma unroll
        for (int a = 0; a < 4; ++a)
            af[a] = *(const bf16x8*)(&Al[(wm * 64 + a * 16 + lm) * 40 + q * 8]);
#pragma unroll
        for (int b = 0; b < 4; ++b)
            bfr[b] = *(const bf16x8*)(&Bl[(wn * 64 + b * 16 + lm) * 40 + q * 8]);
#pragma unroll
        for (int a = 0; a < 4; ++a)
#pragma unroll
            for (int b = 0; b < 4; ++b)
                acc[a][b] = __builtin_amdgcn_mfma_f32_16x16x32_bf16(af[a], bfr[b], acc[a][b], 0, 0, 0);
    }

#pragma unroll
    for (int a = 0; a < 4; ++a) {
        int mrow = m0 + wm * 64 + a * 16 + q * 4;
#pragma unroll
        for (int b = 0; b < 4; ++b) {
            int ncol = n0 + wn * 64 + b * 16 + lm;
            float bias = benc[l * FT + ncol];
#pragma unroll
            for (int r = 0; r < 4; ++r) {
                float v = acc[a][b][r] + bias;
                v = v > 0.f ? v : 0.f;
                feats[(size_t)l * NP * FT + (size_t)(mrow + r) * FT + ncol] = f2bf(v);
            }
        }
    }
}

// ---------- decode: out[j,b,d] += feats[i,b,:]*W_dec[i,j,:,d]  (one (i,j) per block.y) ----------
__global__ __launch_bounds__(256, 2) void decode_gemm(const u16* __restrict__ feats,
                                                      const float* __restrict__ wdec,
                                                      float* __restrict__ out) {
    __shared__ u16 Al[128 * 40];
    __shared__ u16 Bl[128 * 40];
    const int p = blockIdx.y;              // 0..35 triangular pair index
    int j = 0;
    while ((j + 1) * (j + 2) / 2 <= p) ++j;
    const int i = p - j * (j + 1) / 2;
    const int mt = blockIdx.x / 6, nt = blockIdx.x % 6;
    const int m0 = mt * 128, n0 = nt * 128;
    const int t = threadIdx.x;
    const int lane = t & 63, w = t >> 6;
    const int lm = lane & 15, q = lane >> 4;
    const int wm = w >> 1, wn = w & 1;

    const u16*  Ag = feats + (size_t)i * NP * FT + (size_t)(m0 + (t >> 1)) * FT + (t & 1) * 16;
    const float* Bg = wdec + (size_t)(i * NL + j) * FT * DM + n0 + (t & 127);
    const int khalf = (t >> 7) * 16;
    u16* Aw = &Al[(t >> 1) * 40 + (t & 1) * 16];
    u16* Bw = &Bl[(t & 127) * 40 + khalf];

    f32x4 acc[4][4];
#pragma unroll
    for (int a = 0; a < 4; ++a)
#pragma unroll
        for (int b = 0; b < 4; ++b) acc[a][b] = (f32x4){0.f, 0.f, 0.f, 0.f};

    for (int k0 = 0; k0 < FT; k0 += 32) {
        bf16x8 a0 = *(const bf16x8*)(Ag + k0);
        bf16x8 a1 = *(const bf16x8*)(Ag + k0 + 8);
        float v[16];
#pragma unroll
        for (int kk = 0; kk < 16; ++kk)
            v[kk] = Bg[(size_t)(k0 + khalf + kk) * DM];   // lane-contiguous in n -> coalesced
        __syncthreads();
        *(bf16x8*)Aw = a0; *(bf16x8*)(Aw + 8) = a1;
        bf16x8 h0, h1;
#pragma unroll
        for (int kk = 0; kk < 8; ++kk) { h0[kk] = (short)f2bf(v[kk]); h1[kk] = (short)f2bf(v[8 + kk]); }
        *(bf16x8*)Bw = h0; *(bf16x8*)(Bw + 8) = h1;       // transposed store: row n, k contiguous
        __syncthreads();
        bf16x8 af[4], bfr[4];
#pragma unroll
        for (int a = 0; a < 4; ++a)
            af[a] = *(const bf16x8*)(&Al[(wm * 64 + a * 16 + lm) * 40 + q * 8]);
#pragma unroll
        for (int b = 0; b < 4; ++b)
            bfr[b] = *(const bf16x8*)(&Bl[(wn * 64 + b * 16 + lm) * 40 + q * 8]);
#pragma unroll
        for (int a = 0; a < 4; ++a)
#pragma unroll
            for (int b = 0; b < 4; ++b)
                acc[a][b] = __builtin_amdgcn_mfma_f32_16x16x32_bf16(af[a], bfr[b], acc[a][b], 0, 0, 0);
    }

#pragma unroll
    for (int a = 0; a < 4; ++a) {
        int mrow = m0 + wm * 64 + a * 16 + q * 4;
#pragma unroll
        for (int b = 0; b < 4; ++b) {
            int ncol = n0 + wn * 64 + b * 16 + lm;
#pragma unroll
            for (int r = 0; r < 4; ++r)
                atomicAdd(out + (size_t)j * NP * DM + (size_t)(mrow + r) * DM + ncol, acc[a][b][r]);
        }
    }
}

extern "C" void kernel_launch(void* const* d_in, const int* in_sizes, int n_in,
                              void* d_out, int out_size, void* d_ws, size_t ws_size,
                              hipStream_t stream) {
    const float* x     = (const float*)d_in[0];
    const float* W_enc = (const float*)d_in[1];
    const float* b_enc = (const float*)d_in[2];
    const float* W_dec = (const float*)d_in[3];
    const float* b_dec = (const float*)d_in[4];
    float* out = (float*)d_out;

    // workspace: x_bf16 (12.6 MB) | W_enc_bf16 (50.3 MB) | feats_bf16 (67.1 MB)  ~130 MB total
    u16* xb    = (u16*)d_ws;
    u16* wb    = xb + (size_t)NL * NP * DM;
    u16* feats = wb + (size_t)NL * FT * DM;

    cvt_bf16_k<<<(NL * NP * DM / 8 + 255) / 256, 256, 0, stream>>>(x, xb, NL * NP * DM / 8);
    cvt_bf16_k<<<(NL * FT * DM / 8 + 255) / 256, 256, 0, stream>>>(W_enc, wb, NL * FT * DM / 8);
    init_out_k<<<(NL * NP * DM / 4) / 256, 256, 0, stream>>>(out, b_dec);
    encode_gemm<<<dim3(256, 8), 256, 0, stream>>>(xb, wb, b_enc, feats);
    decode_gemm<<<dim3(48, 36), 256, 0, stream>>>(feats, W_dec, out);
}

// Round 2
// 1533.088 us; speedup vs baseline: 1.0742x; 1.0742x over previous
//
#include <hip/hip_runtime.h>

#define NL 8
#define NP 1024
#define DM 768
#define FT 4096

typedef short bf16x8 __attribute__((ext_vector_type(8)));
typedef float f32x4  __attribute__((ext_vector_type(4)));
typedef unsigned short u16;

static __device__ __forceinline__ u16 f2bf(float f) {
    union { float f; unsigned int u; } c; c.f = f;
    unsigned int u = c.u;
    u += 0x7fffu + ((u >> 16) & 1u);   // RNE; inputs finite
    return (u16)(u >> 16);
}

static __device__ __forceinline__ void gload_lds16(const u16* g, u16* l) {
    __builtin_amdgcn_global_load_lds(
        (const __attribute__((address_space(1))) unsigned int*)g,
        (__attribute__((address_space(3))) unsigned int*)l, 16, 0, 0);
}

// ---------- fp32 -> bf16 convert (8 elems / thread) ----------
__global__ __launch_bounds__(256) void cvt_bf16_k(const float* __restrict__ in,
                                                  u16* __restrict__ out, int n8) {
    int i = blockIdx.x * 256 + threadIdx.x;
    if (i >= n8) return;
    const f32x4* p = (const f32x4*)in + (size_t)2 * i;
    f32x4 a = p[0], b = p[1];
    bf16x8 v;
    v[0] = (short)f2bf(a[0]); v[1] = (short)f2bf(a[1]);
    v[2] = (short)f2bf(a[2]); v[3] = (short)f2bf(a[3]);
    v[4] = (short)f2bf(b[0]); v[5] = (short)f2bf(b[1]);
    v[6] = (short)f2bf(b[2]); v[7] = (short)f2bf(b[3]);
    *((bf16x8*)out + i) = v;
}

// ---------- out[j,b,d] = b_dec[j,d] ----------
__global__ __launch_bounds__(256) void init_out_k(float* __restrict__ out,
                                                  const float* __restrict__ bdec) {
    int i = blockIdx.x * 256 + threadIdx.x;
    int e = i * 4;
    int d = e % DM;
    int j = e / (NP * DM);
    f32x4 v = *(const f32x4*)(bdec + j * DM + d);
    *(f32x4*)(out + e) = v;
}

// ---------- W_dec[i,j] (4096x768 fp32, k-major) -> Wt[p] (768x4096 bf16, n-major) ----------
__global__ __launch_bounds__(256) void wdec_transpose(const float* __restrict__ wdec,
                                                      u16* __restrict__ wt) {
    __shared__ float Tl[64 * 65];
    const int p = blockIdx.y;
    int j = 0;
    while ((j + 1) * (j + 2) / 2 <= p) ++j;
    const int i = p - j * (j + 1) / 2;
    const int tx = blockIdx.x & 63;        // f tile 0..63
    const int ty = blockIdx.x >> 6;        // d tile 0..11
    const int f0 = tx * 64, d0 = ty * 64;
    const int t = threadIdx.x;

    const float* src = wdec + (size_t)(i * NL + j) * FT * DM;
    const int fl = t >> 4;                 // 0..15
    const int dl = (t & 15) * 4;
#pragma unroll
    for (int r = 0; r < 4; ++r) {
        int f = fl + r * 16;
        f32x4 v = *(const f32x4*)(src + (size_t)(f0 + f) * DM + d0 + dl);
#pragma unroll
        for (int c = 0; c < 4; ++c) Tl[(dl + c) * 65 + f] = v[c];
    }
    __syncthreads();
    const int dr = t >> 2;                 // 0..63
    const int fo = (t & 3) * 16;
    bf16x8 h0, h1;
#pragma unroll
    for (int c = 0; c < 8; ++c) {
        h0[c] = (short)f2bf(Tl[dr * 65 + fo + c]);
        h1[c] = (short)f2bf(Tl[dr * 65 + fo + 8 + c]);
    }
    u16* dst = wt + (size_t)p * DM * FT + (size_t)(d0 + dr) * FT + f0 + fo;
    *(bf16x8*)dst = h0;
    *(bf16x8*)(dst + 8) = h1;
}

// ---------- encode: feats[l,b,f] = relu(x[l,b,:].W_enc[l,f,:] + b_enc[l,f]) ----------
// BM=256 BN=128 BK=32, global_load_lds staging, unpadded LDS [row][32].
__global__ __launch_bounds__(256, 2) void encode_gemm(const u16* __restrict__ xb,
                                                      const u16* __restrict__ wb,
                                                      const float* __restrict__ benc,
                                                      u16* __restrict__ feats) {
    __shared__ u16 Al[256 * 32];
    __shared__ u16 Bl[128 * 32];
    const int l  = blockIdx.y;
    const int mt = blockIdx.x >> 5;        // 0..3
    const int nt = blockIdx.x & 31;        // 0..31
    const int m0 = mt * 256, n0 = nt * 128;
    const int t = threadIdx.x, lane = t & 63, w = t >> 6;
    const int lm = lane & 15, q = lane >> 4;
    const int r16 = lane >> 2, kq = (lane & 3) * 8;

    const u16* Abase = xb + (size_t)l * NP * DM;
    const u16* Bbase = wb + (size_t)l * FT * DM;

    f32x4 acc[4][8];
#pragma unroll
    for (int a = 0; a < 4; ++a)
#pragma unroll
        for (int b = 0; b < 8; ++b) acc[a][b] = (f32x4){0.f, 0.f, 0.f, 0.f};

    for (int k0 = 0; k0 < DM; k0 += 32) {
#pragma unroll
        for (int s = 0; s < 4; ++s) {
            int c = w + 4 * s;
            gload_lds16(Abase + (size_t)(m0 + c * 16 + r16) * DM + k0 + kq,
                        &Al[c * 512 + lane * 8]);
        }
#pragma unroll
        for (int s = 0; s < 2; ++s) {
            int c = w + 4 * s;
            gload_lds16(Bbase + (size_t)(n0 + c * 16 + r16) * DM + k0 + kq,
                        &Bl[c * 512 + lane * 8]);
        }
        __syncthreads();
        bf16x8 af[4], bfr[8];
#pragma unroll
        for (int a = 0; a < 4; ++a)
            af[a] = *(const bf16x8*)(&Al[(w * 64 + a * 16 + lm) * 32 + q * 8]);
#pragma unroll
        for (int b = 0; b < 8; ++b)
            bfr[b] = *(const bf16x8*)(&Bl[(b * 16 + lm) * 32 + q * 8]);
#pragma unroll
        for (int a = 0; a < 4; ++a)
#pragma unroll
            for (int b = 0; b < 8; ++b)
                acc[a][b] = __builtin_amdgcn_mfma_f32_16x16x32_bf16(af[a], bfr[b], acc[a][b], 0, 0, 0);
        __syncthreads();
    }

#pragma unroll
    for (int a = 0; a < 4; ++a) {
        int mr = m0 + w * 64 + a * 16 + q * 4;
#pragma unroll
        for (int b = 0; b < 8; ++b) {
            int nc = n0 + b * 16 + lm;
            float bias = benc[l * FT + nc];
#pragma unroll
            for (int r = 0; r < 4; ++r) {
                float v = acc[a][b][r] + bias;
                v = v > 0.f ? v : 0.f;
                feats[(size_t)l * NP * FT + (size_t)(mr + r) * FT + nc] = f2bf(v);
            }
        }
    }
}

// ---------- decode: out[j] += feats[i] . Wt[p]^T  (one (i,j) pair per blockIdx.y) ----------
__global__ __launch_bounds__(256, 2) void decode_gemm(const u16* __restrict__ feats,
                                                      const u16* __restrict__ wt,
                                                      float* __restrict__ out) {
    __shared__ u16 Al[256 * 32];
    __shared__ u16 Bl[128 * 32];
    const int p = blockIdx.y;
    int j = 0;
    while ((j + 1) * (j + 2) / 2 <= p) ++j;
    const int i = p - j * (j + 1) / 2;
    const int mt = blockIdx.x / 6, nt = blockIdx.x % 6;
    const int m0 = mt * 256, n0 = nt * 128;
    const int t = threadIdx.x, lane = t & 63, w = t >> 6;
    const int lm = lane & 15, q = lane >> 4;
    const int r16 = lane >> 2, kq = (lane & 3) * 8;

    const u16* Abase = feats + (size_t)i * NP * FT;
    const u16* Bbase = wt + (size_t)p * DM * FT;

    f32x4 acc[4][8];
#pragma unroll
    for (int a = 0; a < 4; ++a)
#pragma unroll
        for (int b = 0; b < 8; ++b) acc[a][b] = (f32x4){0.f, 0.f, 0.f, 0.f};

    for (int k0 = 0; k0 < FT; k0 += 32) {
#pragma unroll
        for (int s = 0; s < 4; ++s) {
            int c = w + 4 * s;
            gload_lds16(Abase + (size_t)(m0 + c * 16 + r16) * FT + k0 + kq,
                        &Al[c * 512 + lane * 8]);
        }
#pragma unroll
        for (int s = 0; s < 2; ++s) {
            int c = w + 4 * s;
            gload_lds16(Bbase + (size_t)(n0 + c * 16 + r16) * FT + k0 + kq,
                        &Bl[c * 512 + lane * 8]);
        }
        __syncthreads();
        bf16x8 af[4], bfr[8];
#pragma unroll
        for (int a = 0; a < 4; ++a)
            af[a] = *(const bf16x8*)(&Al[(w * 64 + a * 16 + lm) * 32 + q * 8]);
#pragma unroll
        for (int b = 0; b < 8; ++b)
            bfr[b] = *(const bf16x8*)(&Bl[(b * 16 + lm) * 32 + q * 8]);
#pragma unroll
        for (int a = 0; a < 4; ++a)
#pragma unroll
            for (int b = 0; b < 8; ++b)
                acc[a][b] = __builtin_amdgcn_mfma_f32_16x16x32_bf16(af[a], bfr[b], acc[a][b], 0, 0, 0);
        __syncthreads();
    }

#pragma unroll
    for (int a = 0; a < 4; ++a) {
        int mr = m0 + w * 64 + a * 16 + q * 4;
#pragma unroll
        for (int b = 0; b < 8; ++b) {
            int nc = n0 + b * 16 + lm;
#pragma unroll
            for (int r = 0; r < 4; ++r)
                atomicAdd(out + (size_t)j * NP * DM + (size_t)(mr + r) * DM + nc, acc[a][b][r]);
        }
    }
}

extern "C" void kernel_launch(void* const* d_in, const int* in_sizes, int n_in,
                              void* d_out, int out_size, void* d_ws, size_t ws_size,
                              hipStream_t stream) {
    const float* x     = (const float*)d_in[0];
    const float* W_enc = (const float*)d_in[1];
    const float* b_enc = (const float*)d_in[2];
    const float* W_dec = (const float*)d_in[3];
    const float* b_dec = (const float*)d_in[4];
    float* out = (float*)d_out;

    // ws: xb 12.6MB | wb 50.3MB | feats 67.1MB | Wt 226.5MB  (~357MB)
    u16* xb    = (u16*)d_ws;
    u16* wb    = xb + (size_t)NL * NP * DM;
    u16* feats = wb + (size_t)NL * FT * DM;
    u16* wt    = feats + (size_t)NL * NP * FT;

    cvt_bf16_k<<<(NL * NP * DM / 8 + 255) / 256, 256, 0, stream>>>(x, xb, NL * NP * DM / 8);
    cvt_bf16_k<<<(NL * FT * DM / 8 + 255) / 256, 256, 0, stream>>>(W_enc, wb, NL * FT * DM / 8);
    init_out_k<<<(NL * NP * DM / 4) / 256, 256, 0, stream>>>(out, b_dec);
    wdec_transpose<<<dim3(768, 36), 256, 0, stream>>>(W_dec, wt);
    encode_gemm<<<dim3(128, 8), 256, 0, stream>>>(xb, wb, b_enc, feats);
    decode_gemm<<<dim3(24, 36), 256, 0, stream>>>(feats, wt, out);
}